// Round 3
// baseline (74.929 us; speedup 1.0000x reference)
//
#include <hip/hip_runtime.h>

#define BIG 1e9f

// wave_shr:1 via DPP: lane j gets src from lane j-1; lane 0 gets `old_v`.
// VALU-pipe cross-lane (v_mov_b32_dpp), ~5 cyc dependent latency.
__device__ __forceinline__ float dpp_shr1(float src, float old_v) {
    return __int_as_float(__builtin_amdgcn_update_dpp(
        __float_as_int(old_v), __float_as_int(src),
        0x138 /* wave_shr:1 */, 0xF, 0xF, false));
}

// One 64-lane wave per sample; lane j owns column j. Anti-diagonal sweep:
// diag k holds cells (i=k-j, j); neighbors are lane j / lane j-1 values of
// diags k-1, k-2 (registers + DPP). LDS holds h = 0.5*img (pre-scaled at
// staging). The per-diagonal LDS read h[k-j][j] is the only memory op in
// the loop; it is prefetched 8 diagonals ahead (depth-8 ring) so its
// ~120-cyc dependent latency is hidden behind the serial DP chain.
__global__ __launch_bounds__(128) void dp_diag_kernel(const float* __restrict__ img,
                                                      float* __restrict__ out, int B) {
    __shared__ float smem[2][4096];   // 16 KB per wave
    const int lane = threadIdx.x & 63;
    const int wave = threadIdx.x >> 6;
    const int b = (blockIdx.x << 1) + wave;
    const bool active = (b < B);

    float* s = smem[wave];
    if (active) {
        // coalesced float4 stage, pre-multiplied by 0.5 (exact: pow2 scale)
        const float4* g4 = (const float4*)(img + ((size_t)b << 12));
        float4* s4 = (float4*)s;
        #pragma unroll
        for (int t = 0; t < 16; ++t) {
            float4 v = g4[(t << 6) + lane];
            v.x *= 0.5f; v.y *= 0.5f; v.z *= 0.5f; v.w *= 0.5f;
            s4[(t << 6) + lane] = v;
        }
    }
    __syncthreads();   // unguarded: no barrier divergence if B odd

    if (active) {
        // diag k=0 state: cell (0,0)=0, rest BIG.
        float d_prev = (lane == 0) ? 0.0f : BIG;  // d on diag k-1 (lane j)
        float d_pp   = BIG;                       // d on diag k-2 (lane j)
        float h_prev   = s[lane];                 // 0.5*img[0][j]
        float hm1_prev = 0.0f;                    // feeds only BIG-guarded c3 at k=1

        // h[clamp(k-lane)][lane]; clamped reads (k>126-ish) are safe in-bounds.
        auto rd = [&](int k) -> float {
            int i  = k - lane;
            int ic = i < 0 ? 0 : (i > 63 ? 63 : i);   // v_med3_i32
            return s[(ic << 6) | lane];               // bank lane%32: conflict-free
        };

        auto step = [&](float h) {
            float hm1   = dpp_shr1(h_prev, 0.0f);   // 0.5*img[i][j-1]
            float shd   = dpp_shr1(d_prev, BIG);    // d[i][j-1]
            float shdpp = dpp_shr1(d_pp,   BIG);    // d[i-1][j-1]
            // off-critical-path min (down, diag); critical: dpp->add->min->add
            float m = fminf(d_prev + h_prev, shdpp + hm1_prev);
            float d = fminf(shd + hm1, m) + h;
            d_pp = d_prev; d_prev = d; hm1_prev = hm1; h_prev = h;
        };

        // depth-8 prefetch ring over diagonals k=1..126
        float pf0 = rd(1), pf1 = rd(2), pf2 = rd(3), pf3 = rd(4);
        float pf4 = rd(5), pf5 = rd(6), pf6 = rd(7), pf7 = rd(8);

        int k = 1;
        #pragma unroll 1
        for (int g = 0; g < 15; ++g, k += 8) {      // k = 1..120
            float h0 = pf0, h1 = pf1, h2 = pf2, h3 = pf3;
            float h4 = pf4, h5 = pf5, h6 = pf6, h7 = pf7;
            pf0 = rd(k + 8);  pf1 = rd(k + 9);  pf2 = rd(k + 10); pf3 = rd(k + 11);
            pf4 = rd(k + 12); pf5 = rd(k + 13); pf6 = rd(k + 14); pf7 = rd(k + 15);
            step(h0); step(h1); step(h2); step(h3);
            step(h4); step(h5); step(h6); step(h7);
        }
        // tail: k = 121..126
        step(pf0); step(pf1); step(pf2); step(pf3); step(pf4); step(pf5);

        if (lane == 63) out[b] = d_prev;   // d[63][63] lives on diag 126, lane 63
    }
}

extern "C" void kernel_launch(void* const* d_in, const int* in_sizes, int n_in,
                              void* d_out, int out_size, void* d_ws, size_t ws_size,
                              hipStream_t stream) {
    const float* img = (const float*)d_in[0];
    float* out = (float*)d_out;
    const int B = out_size;                  // 2048
    const int threads = 128;                 // 2 waves (samples) per block
    const int grid = (B + 1) / 2;
    dp_diag_kernel<<<grid, threads, 0, stream>>>(img, out, B);
}

// Round 4
// 74.276 us; speedup vs baseline: 1.0088x; 1.0088x over previous
//
#include <hip/hip_runtime.h>

#define BIG 1e9f

// wave_shr:1, lane 0 receives BIG (old operand). v_mov_b32_dpp, VALU pipe.
__device__ __forceinline__ float dpp_shr1_big(float src) {
    return __int_as_float(__builtin_amdgcn_update_dpp(
        __float_as_int(BIG), __float_as_int(src),
        0x138 /* wave_shr:1 */, 0xF, 0xF, false));
}

// One 64-lane wave per sample; lane j owns column j; anti-diagonal sweep.
// Potential transform: e[v] = d[v] + h[v] (h = img/2) turns the DP into
//   e[v] = img[v] + min3(e_left, e_up, e_diag),  e[0][0] = 0.5*img[0][0]
// so each diagonal is just: x = shr1(e); m = min3(x, e, x_stale); e = m + w.
// x_stale (= shr1 of e from two diags back) supplies the diag edge for free.
// Answer: d[63][63] = e_final - 0.5*img[63][63].
// Lanes outside their active range [j, j+63] carry ~BIG values that drift
// upward only and are never consumed by an in-range cell (checked at both
// activation k=j and retirement k=j+63 boundaries).
__global__ __launch_bounds__(128) void dp_diag_kernel(const float* __restrict__ img,
                                                      float* __restrict__ out, int B) {
    __shared__ float smem[2][4096];   // raw image, 16 KB per wave
    const int lane = threadIdx.x & 63;
    const int wave = threadIdx.x >> 6;
    const int b = (blockIdx.x << 1) + wave;
    const bool active = (b < B);

    float* s = smem[wave];
    if (active) {
        const float4* g4 = (const float4*)(img + ((size_t)b << 12));
        float4* s4 = (float4*)s;
        #pragma unroll
        for (int t = 0; t < 16; ++t)
            s4[(t << 6) + lane] = g4[(t << 6) + lane];   // coalesced 1 KB/instr
    }
    __syncthreads();   // unguarded: no barrier divergence

    if (active) {
        // w[k] = img[clamp(k-lane)][lane]; clamped reads stay in-bounds.
        auto rd = [&](int k) -> float {
            int i  = k - lane;
            int ic = i < 0 ? 0 : (i > 63 ? 63 : i);   // v_med3_i32
            return s[(ic << 6) | lane];               // bank lane%32: conflict-free
        };

        float e  = (lane == 0) ? 0.5f * s[0] : BIG;   // diag k=0 state
        float xs = BIG;                               // shr1(e) from two diags back

        auto step = [&](float w) {
            float x = dpp_shr1_big(e);                // e_left
            float m = fminf(fminf(x, e), xs);         // v_min3: left, up, diag
            e  = m + w;
            xs = x;
        };

        // depth-8 prefetch ring over diagonals k = 1..126
        float pf0 = rd(1), pf1 = rd(2), pf2 = rd(3), pf3 = rd(4);
        float pf4 = rd(5), pf5 = rd(6), pf6 = rd(7), pf7 = rd(8);

        int k = 1;
        #pragma unroll 1
        for (int g = 0; g < 15; ++g, k += 8) {        // k = 1..120
            float h0 = pf0, h1 = pf1, h2 = pf2, h3 = pf3;
            float h4 = pf4, h5 = pf5, h6 = pf6, h7 = pf7;
            pf0 = rd(k + 8);  pf1 = rd(k + 9);  pf2 = rd(k + 10); pf3 = rd(k + 11);
            pf4 = rd(k + 12); pf5 = rd(k + 13); pf6 = rd(k + 14); pf7 = rd(k + 15);
            step(h0); step(h1); step(h2); step(h3);
            step(h4); step(h5); step(h6); step(h7);
        }
        // tail: k = 121..126
        step(pf0); step(pf1); step(pf2); step(pf3); step(pf4); step(pf5);

        if (lane == 63) out[b] = e - 0.5f * s[4095];  // d[63][63]
    }
}

extern "C" void kernel_launch(void* const* d_in, const int* in_sizes, int n_in,
                              void* d_out, int out_size, void* d_ws, size_t ws_size,
                              hipStream_t stream) {
    const float* img = (const float*)d_in[0];
    float* out = (float*)d_out;
    const int B = out_size;                  // 2048
    const int threads = 128;                 // 2 waves (samples) per block
    const int grid = (B + 1) / 2;
    dp_diag_kernel<<<grid, threads, 0, stream>>>(img, out, B);
}

// Round 5
// 73.500 us; speedup vs baseline: 1.0194x; 1.0106x over previous
//
#include <hip/hip_runtime.h>

#define BIG 1e9f

// ---- asm macros -----------------------------------------------------------
// RD(W): advance per-lane diag counter ik (= k - lane), clamp row to [0,63],
//        form LDS byte addr = row*256 + (base + lane*4), issue ds_read_b32.
#define RD(W) \
    "v_add_u32 %[ik], 1, %[ik]\n\t" \
    "v_med3_i32 %[ic], %[ik], 0, 63\n\t" \
    "v_lshl_add_u32 %[ad], %[ic], 8, %[sb]\n\t" \
    "ds_read_b32 " W ", %[ad]\n\t"

// CMP(W,XN,XO): allow 12 reads outstanding (oldest = this step's w is done),
//               x = wave_shr:1(e) with lane0 <- BIG (masked-write DPP keeps
//               the preloaded BIG), e = min3(left, up, diag) + w.
#define CMP(W, XN, XO) \
    "s_waitcnt lgkmcnt(12)\n\t" \
    "v_mov_b32 " XN ", %[vbig]\n\t" \
    "v_mov_b32_dpp " XN ", %[e] wave_shr:1 row_mask:0xf bank_mask:0xf\n\t" \
    "v_min3_f32 %[tp], " XN ", %[e], " XO "\n\t" \
    "v_add_f32 %[e], %[tp], " W "\n\t"

#define SLOT(WISS, WCON, XN, XO) RD(WISS) CMP(WCON, XN, XO)

// One 64-lane wave per sample; lane j owns column j; anti-diagonal sweep with
// potential transform e[v] = d[v] + img[v]/2:
//   e[v] = img[v] + min3(e_left, e_up, e_diag),  answer = e_final - img[63][63]/2.
// The 126-step serial chain is hand-scheduled in inline asm: LDS reads run
// 12 diagonals ahead of their consumers (ring of 14 w-regs), so the ~120-cyc
// ds_read latency is fully hidden; the compiler cannot reorder or re-waitcnt
// inside the block.
__global__ __launch_bounds__(128) void dp_diag_kernel(const float* __restrict__ img,
                                                      float* __restrict__ out, int B) {
    __shared__ __align__(16) float smem[2][4096];   // 16 KB per wave, wave-private
    const int lane = threadIdx.x & 63;
    const int wave = threadIdx.x >> 6;
    const int b = (blockIdx.x << 1) + wave;
    if (b >= B) return;                // uniform per wave; no block barrier used

    float* s = smem[wave];
    {   // coalesced float4 staging, row-major s[i*64+j]
        const float4* g4 = (const float4*)(img + ((size_t)b << 12));
        float4* s4 = (float4*)s;
        #pragma unroll
        for (int t = 0; t < 16; ++t)
            s4[(t << 6) + lane] = g4[(t << 6) + lane];
    }
    // no __syncthreads: each wave reads only its own region; same-wave DS ops
    // complete in order, and the first lgkmcnt(12) drains the older writes.

    float e  = (lane == 0) ? 0.5f * s[0] : BIG;   // diag k=0 state
    float x0 = BIG, x1 = BIG;                     // rotating shr1 regs (diag term)
    float w0 = 0, w1 = 0, w2 = 0, w3 = 0, w4 = 0, w5 = 0, w6 = 0,
          w7 = 0, w8 = 0, w9 = 0, w10 = 0, w11 = 0, w12 = 0, w13 = 0;
    int ik = -lane;                               // k - lane, pre-first-increment
    int ic = 0; unsigned ad = 0; float tp = 0;
    const float    vbig  = BIG;
    const unsigned sbase = (unsigned)(uintptr_t)s + ((unsigned)lane << 2);

    // prologue: issue reads for diagonals k = 1..12 into w1..w12
    asm volatile(
        RD("%[w1]") RD("%[w2]") RD("%[w3]") RD("%[w4]") RD("%[w5]") RD("%[w6]")
        RD("%[w7]") RD("%[w8]") RD("%[w9]") RD("%[w10]") RD("%[w11]") RD("%[w12]")
        "s_nop 2\n\t"      // VALU->DPP hazard guard for first body step
        : [ik]"+v"(ik), [ic]"+v"(ic), [ad]"+v"(ad),
          [w1]"+v"(w1), [w2]"+v"(w2), [w3]"+v"(w3), [w4]"+v"(w4),
          [w5]"+v"(w5), [w6]"+v"(w6), [w7]"+v"(w7), [w8]"+v"(w8),
          [w9]"+v"(w9), [w10]"+v"(w10), [w11]"+v"(w11), [w12]"+v"(w12)
        : [sb]"v"(sbase)
        : "memory");

    // body: 9 x 14 slots = steps k = 1..126; slot s issues read k+12 into
    // w[(s+12)%14] and consumes w[s%14]; x0/x1 alternate (xs = prev x).
    #pragma unroll 1
    for (int it = 0; it < 9; ++it) {
        asm volatile(
            SLOT("%[w13]", "%[w1]",  "%[x0]", "%[x1]")
            SLOT("%[w0]",  "%[w2]",  "%[x1]", "%[x0]")
            SLOT("%[w1]",  "%[w3]",  "%[x0]", "%[x1]")
            SLOT("%[w2]",  "%[w4]",  "%[x1]", "%[x0]")
            SLOT("%[w3]",  "%[w5]",  "%[x0]", "%[x1]")
            SLOT("%[w4]",  "%[w6]",  "%[x1]", "%[x0]")
            SLOT("%[w5]",  "%[w7]",  "%[x0]", "%[x1]")
            SLOT("%[w6]",  "%[w8]",  "%[x1]", "%[x0]")
            SLOT("%[w7]",  "%[w9]",  "%[x0]", "%[x1]")
            SLOT("%[w8]",  "%[w10]", "%[x1]", "%[x0]")
            SLOT("%[w9]",  "%[w11]", "%[x0]", "%[x1]")
            SLOT("%[w10]", "%[w12]", "%[x1]", "%[x0]")
            SLOT("%[w11]", "%[w13]", "%[x0]", "%[x1]")
            SLOT("%[w12]", "%[w0]",  "%[x1]", "%[x0]")
            : [e]"+v"(e), [x0]"+v"(x0), [x1]"+v"(x1), [tp]"+v"(tp),
              [ik]"+v"(ik), [ic]"+v"(ic), [ad]"+v"(ad),
              [w0]"+v"(w0), [w1]"+v"(w1), [w2]"+v"(w2), [w3]"+v"(w3),
              [w4]"+v"(w4), [w5]"+v"(w5), [w6]"+v"(w6), [w7]"+v"(w7),
              [w8]"+v"(w8), [w9]"+v"(w9), [w10]"+v"(w10), [w11]"+v"(w11),
              [w12]"+v"(w12), [w13]"+v"(w13)
            : [sb]"v"(sbase), [vbig]"v"(vbig)
            : "memory");
    }
    asm volatile("s_waitcnt lgkmcnt(0)\n\t" ::: "memory");  // drain 12 dangling reads

    if (lane == 63) out[b] = e - 0.5f * s[4095];  // d[63][63]
}

extern "C" void kernel_launch(void* const* d_in, const int* in_sizes, int n_in,
                              void* d_out, int out_size, void* d_ws, size_t ws_size,
                              hipStream_t stream) {
    const float* img = (const float*)d_in[0];
    float* out = (float*)d_out;
    const int B = out_size;                  // 2048
    const int threads = 128;                 // 2 waves (samples) per block
    const int grid = (B + 1) / 2;
    dp_diag_kernel<<<grid, threads, 0, stream>>>(img, out, B);
}